// Round 2
// baseline (663.054 us; speedup 1.0000x reference)
//
#include <hip/hip_runtime.h>
#include <math.h>

#define NEG_SLOPE 0.01f
#define NEG_BIG  -1e30f   // finite sentinel: -INFINITY gives (-inf)-(-inf)=NaN in the
                          // shuffle combine for deg<32 nodes -> l=NaN -> inv_l=0 -> zeroed row

// ---------------- CSR build ----------------

__global__ void count_deg_kernel(const int* __restrict__ dst, int* __restrict__ deg, int E) {
    int e = blockIdx.x * blockDim.x + threadIdx.x;
    if (e < E) atomicAdd(&deg[dst[e]], 1);
}

// single-block exclusive scan (n ~ 50k)
__global__ void scan_kernel(const int* __restrict__ deg, int* __restrict__ row_ptr, int n) {
    __shared__ int sm[1024];
    int carry = 0;
    for (int base = 0; base < n; base += 1024) {
        int i = base + (int)threadIdx.x;
        int x = (i < n) ? deg[i] : 0;
        sm[threadIdx.x] = x;
        __syncthreads();
        for (int off = 1; off < 1024; off <<= 1) {
            int y = (threadIdx.x >= (unsigned)off) ? sm[threadIdx.x - off] : 0;
            __syncthreads();
            sm[threadIdx.x] += y;
            __syncthreads();
        }
        int incl = sm[threadIdx.x];
        if (i < n) row_ptr[i] = carry + incl - x;   // exclusive prefix
        carry += sm[1023];
        __syncthreads();
    }
    if (threadIdx.x == 0) row_ptr[n] = carry;
}

__global__ void scatter_kernel(const int* __restrict__ src, const int* __restrict__ dst,
                               const int* __restrict__ row_ptr, int* __restrict__ cur,
                               int* __restrict__ csr_src, int E) {
    int e = blockIdx.x * blockDim.x + threadIdx.x;
    if (e < E) {
        int d = dst[e];
        int pos = atomicAdd(&cur[d], 1);
        csr_src[row_ptr[d] + pos] = src[e];
    }
}

// ---------------- per-layer kernels ----------------

// one wave (64 lanes) per node: s[v] = h[v].w_src, t[v] = h[v].w_dst
__global__ void st_kernel(const float* __restrict__ h, const float* __restrict__ att_w_l,
                          float* __restrict__ s, float* __restrict__ t, int n) {
    int gid  = blockIdx.x * blockDim.x + threadIdx.x;
    int v    = gid >> 6;
    int lane = threadIdx.x & 63;
    if (v >= n) return;
    float2 hv = ((const float2*)(h + (size_t)v * 128))[lane];
    float2 ws = ((const float2*)att_w_l)[lane];
    float2 wd = ((const float2*)(att_w_l + 128))[lane];
    float ps = hv.x * ws.x + hv.y * ws.y;
    float pt = hv.x * wd.x + hv.y * wd.y;
    for (int off = 32; off > 0; off >>= 1) {
        ps += __shfl_down(ps, off);
        pt += __shfl_down(pt, off);
    }
    if (lane == 0) { s[v] = ps; t[v] = pt; }
}

// one wave per node: online softmax over its in-edges, then weighted gather
__global__ void agg_kernel(const float* __restrict__ hin, const float* __restrict__ s,
                           const float* __restrict__ t, const int* __restrict__ row_ptr,
                           const int* __restrict__ csr_src, float* __restrict__ hout, int n) {
    int gid  = blockIdx.x * blockDim.x + threadIdx.x;
    int v    = gid >> 6;
    int lane = threadIdx.x & 63;
    if (v >= n) return;

    int beg = row_ptr[v];
    int end = row_ptr[v + 1];
    float tv = t[v];

    // phase A: online softmax (m, l) per lane over strided edges
    float m = NEG_BIG, l = 0.f;
    for (int i = beg + lane; i < end; i += 64) {
        int u = csr_src[i];
        float a = s[u] + tv;
        float e = (a > 0.f) ? a : NEG_SLOPE * a;
        float mn = fmaxf(m, e);
        l = l * __expf(m - mn) + __expf(e - mn);   // exp(-1e30)=0 covers first iter; no NaN
        m = mn;
    }
    // combine (m,l) across 64 lanes — finite sentinel keeps m-mn NaN-free
    for (int off = 32; off > 0; off >>= 1) {
        float m2 = __shfl_down(m, off);
        float l2 = __shfl_down(l, off);
        float mn = fmaxf(m, m2);
        l = l * __expf(m - mn) + l2 * __expf(m2 - mn);
        m = mn;
    }
    m = __shfl(m, 0);
    l = __shfl(l, 0);
    float inv_l = (l > 0.f) ? (1.0f / l) : 0.f;    // deg-0 node -> zero row (matches ref)

    // phase B: every lane owns 2 feature dims; recompute alpha per edge (broadcast loads)
    float2 acc = make_float2(0.f, 0.f);
    for (int i = beg; i < end; ++i) {
        int u = csr_src[i];                         // wave-uniform -> broadcast
        float a = s[u] + tv;
        float e = (a > 0.f) ? a : NEG_SLOPE * a;
        float alpha = __expf(e - m) * inv_l;
        float2 hv = ((const float2*)(hin + (size_t)u * 128))[lane];  // 512B/edge, coalesced
        acc.x = fmaf(alpha, hv.x, acc.x);
        acc.y = fmaf(alpha, hv.y, acc.y);
    }
    ((float2*)(hout + (size_t)v * 128))[lane] = acc;
}

// ---------------- launch ----------------

extern "C" void kernel_launch(void* const* d_in, const int* in_sizes, int n_in,
                              void* d_out, int out_size, void* d_ws, size_t ws_size,
                              hipStream_t stream) {
    const float* h0    = (const float*)d_in[0];
    const int*   src   = (const int*)d_in[1];
    const int*   dst   = (const int*)d_in[2];
    const float* att_w = (const float*)d_in[3];
    int N = in_sizes[0] / 128;
    int E = in_sizes[1];
    int L = in_sizes[3] / 256;
    float* out = (float*)d_out;

    char* ws = (char*)d_ws;
    size_t off = 0;
    auto alloc = [&](size_t bytes) -> void* {
        void* p = ws + off;
        off = (off + bytes + 511) & ~(size_t)511;
        return p;
    };
    int*   deg     = (int*)  alloc((size_t)N * 4);
    int*   row_ptr = (int*)  alloc((size_t)(N + 1) * 4);
    int*   cur     = (int*)  alloc((size_t)N * 4);
    int*   csr_src = (int*)  alloc((size_t)E * 4);
    float* s       = (float*)alloc((size_t)N * 4);
    float* t       = (float*)alloc((size_t)N * 4);
    float* h1      = (float*)alloc((size_t)N * 128 * 4);

    hipMemsetAsync(deg, 0, (size_t)N * 4, stream);
    hipMemsetAsync(cur, 0, (size_t)N * 4, stream);

    const int tb = 256;
    count_deg_kernel<<<(E + tb - 1) / tb, tb, 0, stream>>>(dst, deg, E);
    scan_kernel<<<1, 1024, 0, stream>>>(deg, row_ptr, N);
    scatter_kernel<<<(E + tb - 1) / tb, tb, 0, stream>>>(src, dst, row_ptr, cur, csr_src, E);

    int node_blocks = (N * 64 + tb - 1) / tb;   // one wave per node
    const float* hin = h0;
    for (int l = 0; l < L; ++l) {
        float* hout = (l == L - 1) ? out : h1;   // L==2: layer0 -> h1, layer1 -> out
        st_kernel<<<node_blocks, tb, 0, stream>>>(hin, att_w + (size_t)l * 256, s, t, N);
        agg_kernel<<<node_blocks, tb, 0, stream>>>(hin, s, t, row_ptr, csr_src, hout, N);
        hin = h1;
    }
}

// Round 3
// 478.995 us; speedup vs baseline: 1.3843x; 1.3843x over previous
//
#include <hip/hip_runtime.h>
#include <math.h>

#define NEG_SLOPE 0.01f
#define NEG_BIG  -1e30f   // finite sentinel: -INFINITY gives NaN in shuffle combine for deg<32

// ---------------- CSR build ----------------

__global__ void count_deg_kernel(const int* __restrict__ dst, int* __restrict__ deg, int E) {
    int e = blockIdx.x * blockDim.x + threadIdx.x;
    if (e < E) atomicAdd(&deg[dst[e]], 1);
}

// multi-block scan, stage 1: per-1024-chunk exclusive scan + chunk total
__global__ void scan1_kernel(const int* __restrict__ deg, int* __restrict__ local_excl,
                             int* __restrict__ partials, int n) {
    __shared__ int sm[1024];
    int i = blockIdx.x * 1024 + threadIdx.x;
    int x = (i < n) ? deg[i] : 0;
    sm[threadIdx.x] = x;
    __syncthreads();
    for (int off = 1; off < 1024; off <<= 1) {
        int y = (threadIdx.x >= (unsigned)off) ? sm[threadIdx.x - off] : 0;
        __syncthreads();
        sm[threadIdx.x] += y;
        __syncthreads();
    }
    if (i < n) local_excl[i] = sm[threadIdx.x] - x;
    if (threadIdx.x == 1023) partials[blockIdx.x] = sm[1023];
}

// stage 2: one wave scans the (<=64) chunk totals -> exclusive offsets + grand total
__global__ void scan2_kernel(int* __restrict__ partials, int nchunks) {
    int lane = threadIdx.x & 63;
    int v = (lane < nchunks) ? partials[lane] : 0;
    int incl = v;
    for (int off = 1; off < 64; off <<= 1) {
        int y = __shfl_up(incl, off);
        if (lane >= off) incl += y;
    }
    partials[lane] = incl - v;          // exclusive
    if (lane == 63) partials[64] = incl; // grand total
}

// stage 3: add chunk offset; also writes row_ptr[n]
__global__ void scan3_kernel(const int* __restrict__ local_excl, const int* __restrict__ partials,
                             int* __restrict__ row_ptr, int n) {
    int i = blockIdx.x * 1024 + threadIdx.x;
    if (i < n) row_ptr[i] = local_excl[i] + partials[blockIdx.x];
    if (i == n) row_ptr[n] = partials[64];
}

__global__ void scatter_kernel(const int* __restrict__ src, const int* __restrict__ dst,
                               const int* __restrict__ row_ptr, int* __restrict__ cur,
                               int* __restrict__ csr_src, int E) {
    int e = blockIdx.x * blockDim.x + threadIdx.x;
    if (e < E) {
        int d = dst[e];
        int pos = atomicAdd(&cur[d], 1);
        csr_src[row_ptr[d] + pos] = src[e];
    }
}

// ---------------- per-layer kernels ----------------

// one wave (64 lanes) per node: s[v] = h[v].w_src, t[v] = h[v].w_dst
__global__ void st_kernel(const float* __restrict__ h, const float* __restrict__ att_w_l,
                          float* __restrict__ s, float* __restrict__ t, int n) {
    int gid  = blockIdx.x * blockDim.x + threadIdx.x;
    int v    = gid >> 6;
    int lane = threadIdx.x & 63;
    if (v >= n) return;
    float2 hv = ((const float2*)(h + (size_t)v * 128))[lane];
    float2 ws = ((const float2*)att_w_l)[lane];
    float2 wd = ((const float2*)(att_w_l + 128))[lane];
    float ps = hv.x * ws.x + hv.y * ws.y;
    float pt = hv.x * wd.x + hv.y * wd.y;
    for (int off = 32; off > 0; off >>= 1) {
        ps += __shfl_down(ps, off);
        pt += __shfl_down(pt, off);
    }
    if (lane == 0) { s[v] = ps; t[v] = pt; }
}

// one wave per node: online softmax over in-edges, then weighted float4 gather
// phase B: half-wave per edge (lane&31 owns 4 dims), 2 pairs unrolled = 4 edges in flight
__global__ void agg_kernel(const float* __restrict__ hin, const float* __restrict__ s,
                           const float* __restrict__ t, const int* __restrict__ row_ptr,
                           const int* __restrict__ csr_src, float* __restrict__ hout, int n) {
    int gid   = blockIdx.x * blockDim.x + threadIdx.x;
    int v     = gid >> 6;
    int lane  = threadIdx.x & 63;
    if (v >= n) return;
    int half  = lane >> 5;    // 0 or 1: which edge of the pair
    int hlane = lane & 31;    // feature quad owner: dims 4*hlane..4*hlane+3

    int beg = row_ptr[v];
    int end = row_ptr[v + 1];
    float tv = t[v];

    // phase A: online softmax (m, l), lane-strided
    float m = NEG_BIG, l = 0.f;
    for (int i = beg + lane; i < end; i += 64) {
        int u = csr_src[i];
        float a = s[u] + tv;
        float e = (a > 0.f) ? a : NEG_SLOPE * a;
        float mn = fmaxf(m, e);
        l = l * __expf(m - mn) + __expf(e - mn);
        m = mn;
    }
    for (int off = 32; off > 0; off >>= 1) {
        float m2 = __shfl_down(m, off);
        float l2 = __shfl_down(l, off);
        float mn = fmaxf(m, m2);
        l = l * __expf(m - mn) + l2 * __expf(m2 - mn);
        m = mn;
    }
    m = __shfl(m, 0);
    l = __shfl(l, 0);
    float inv_l = (l > 0.f) ? (1.0f / l) : 0.f;   // deg-0 -> zero row, matches ref

    // phase B
    float4 acc = make_float4(0.f, 0.f, 0.f, 0.f);
    int i = beg;
    for (; i + 3 < end; i += 4) {                 // 4 edges, 2 independent gather chains
        int u0 = csr_src[i + half];
        int u1 = csr_src[i + 2 + half];
        float a0 = s[u0] + tv;
        float a1 = s[u1] + tv;
        const float4* p0 = (const float4*)(hin + (size_t)u0 * 128);
        const float4* p1 = (const float4*)(hin + (size_t)u1 * 128);
        float4 h0 = p0[hlane];
        float4 h1 = p1[hlane];
        float e0 = (a0 > 0.f) ? a0 : NEG_SLOPE * a0;
        float e1 = (a1 > 0.f) ? a1 : NEG_SLOPE * a1;
        float al0 = __expf(e0 - m) * inv_l;
        float al1 = __expf(e1 - m) * inv_l;
        acc.x = fmaf(al0, h0.x, acc.x); acc.y = fmaf(al0, h0.y, acc.y);
        acc.z = fmaf(al0, h0.z, acc.z); acc.w = fmaf(al0, h0.w, acc.w);
        acc.x = fmaf(al1, h1.x, acc.x); acc.y = fmaf(al1, h1.y, acc.y);
        acc.z = fmaf(al1, h1.z, acc.z); acc.w = fmaf(al1, h1.w, acc.w);
    }
    for (; i + 1 < end; i += 2) {                 // leftover pair
        int u = csr_src[i + half];
        float a = s[u] + tv;
        float e = (a > 0.f) ? a : NEG_SLOPE * a;
        float al = __expf(e - m) * inv_l;
        float4 hv = ((const float4*)(hin + (size_t)u * 128))[hlane];
        acc.x = fmaf(al, hv.x, acc.x); acc.y = fmaf(al, hv.y, acc.y);
        acc.z = fmaf(al, hv.z, acc.z); acc.w = fmaf(al, hv.w, acc.w);
    }
    if (i < end) {                                // odd tail: half 1 contributes 0
        int u = csr_src[i];
        float a = s[u] + tv;
        float e = (a > 0.f) ? a : NEG_SLOPE * a;
        float al = (half == 0) ? __expf(e - m) * inv_l : 0.f;
        float4 hv = ((const float4*)(hin + (size_t)u * 128))[hlane];
        acc.x = fmaf(al, hv.x, acc.x); acc.y = fmaf(al, hv.y, acc.y);
        acc.z = fmaf(al, hv.z, acc.z); acc.w = fmaf(al, hv.w, acc.w);
    }
    // combine the two half-wave partial sums (same dims, different edge parity)
    acc.x += __shfl_xor(acc.x, 32);
    acc.y += __shfl_xor(acc.y, 32);
    acc.z += __shfl_xor(acc.z, 32);
    acc.w += __shfl_xor(acc.w, 32);
    if (half == 0)
        ((float4*)(hout + (size_t)v * 128))[hlane] = acc;
}

// ---------------- launch ----------------

extern "C" void kernel_launch(void* const* d_in, const int* in_sizes, int n_in,
                              void* d_out, int out_size, void* d_ws, size_t ws_size,
                              hipStream_t stream) {
    const float* h0    = (const float*)d_in[0];
    const int*   src   = (const int*)d_in[1];
    const int*   dst   = (const int*)d_in[2];
    const float* att_w = (const float*)d_in[3];
    int N = in_sizes[0] / 128;
    int E = in_sizes[1];
    int L = in_sizes[3] / 256;
    float* out = (float*)d_out;

    char* ws = (char*)d_ws;
    size_t off = 0;
    auto alloc = [&](size_t bytes) -> void* {
        void* p = ws + off;
        off = (off + bytes + 511) & ~(size_t)511;
        return p;
    };
    int*   deg       = (int*)  alloc((size_t)N * 4);
    int*   row_ptr   = (int*)  alloc((size_t)(N + 1) * 4);
    int*   cur       = (int*)  alloc((size_t)N * 4);
    int*   csr_src   = (int*)  alloc((size_t)E * 4);
    float* s         = (float*)alloc((size_t)N * 4);
    float* t         = (float*)alloc((size_t)N * 4);
    float* h1        = (float*)alloc((size_t)N * 128 * 4);
    int*   local_ex  = (int*)  alloc((size_t)N * 4);
    int*   partials  = (int*)  alloc(65 * 4);

    hipMemsetAsync(deg, 0, (size_t)N * 4, stream);
    hipMemsetAsync(cur, 0, (size_t)N * 4, stream);

    const int tb = 256;
    int nchunks = (N + 1023) / 1024;   // 49 for N=50000; scan2 assumes <= 64
    count_deg_kernel<<<(E + tb - 1) / tb, tb, 0, stream>>>(dst, deg, E);
    scan1_kernel<<<nchunks, 1024, 0, stream>>>(deg, local_ex, partials, N);
    scan2_kernel<<<1, 64, 0, stream>>>(partials, nchunks);
    scan3_kernel<<<nchunks, 1024, 0, stream>>>(local_ex, partials, row_ptr, N);
    scatter_kernel<<<(E + tb - 1) / tb, tb, 0, stream>>>(src, dst, row_ptr, cur, csr_src, E);

    int node_blocks = (N * 64 + tb - 1) / tb;   // one wave per node
    const float* hin = h0;
    for (int l = 0; l < L; ++l) {
        float* hout = (l == L - 1) ? out : h1;   // L==2: layer0 -> h1, layer1 -> out
        st_kernel<<<node_blocks, tb, 0, stream>>>(hin, att_w + (size_t)l * 256, s, t, N);
        agg_kernel<<<node_blocks, tb, 0, stream>>>(hin, s, t, row_ptr, csr_src, hout, N);
        hin = h1;
    }
}

// Round 4
// 368.584 us; speedup vs baseline: 1.7989x; 1.2996x over previous
//
#include <hip/hip_runtime.h>
#include <math.h>

#define NEG_SLOPE 0.01f
#define NEG_BIG  -1e30f   // finite sentinel: -INFINITY gives NaN in shuffle combine for deg<32
#define BKT_BITS 7        // 128 nodes per bucket
#define BKT_MASK 127
#define SBLOCKS  128      // blocks in the multisplit phases

// NOTE: packing (src<<7)|(dst&127) into 32 bits requires N < 2^25 and relies on
// N = 50000 < 65536 for src; this problem fixes N at 50000.

// ---------------- bucketed CSR build ----------------

// S1: per-(block,bucket) histogram of dst>>7. blockhist[k*SBLOCKS + b].
__global__ void bkhist_kernel(const int* __restrict__ dst, int* __restrict__ blockhist,
                              int E, int NB, int chunk) {
    extern __shared__ int lh[];                      // NB counters
    for (int k = threadIdx.x; k < NB; k += blockDim.x) lh[k] = 0;
    __syncthreads();
    int b = blockIdx.x;
    int beg = b * chunk, end = min(E, beg + chunk);
    for (int e = beg + (int)threadIdx.x; e < end; e += blockDim.x)
        atomicAdd(&lh[dst[e] >> BKT_BITS], 1);
    __syncthreads();
    for (int k = threadIdx.x; k < NB; k += blockDim.x)
        blockhist[k * SBLOCKS + b] = lh[k];
}

// generic multi-block scan, stage 1: per-1024-chunk exclusive scan + chunk totals
__global__ void scan1_kernel(const int* __restrict__ in, int* __restrict__ local_excl,
                             int* __restrict__ partials, int n) {
    __shared__ int sm[1024];
    int i = blockIdx.x * 1024 + threadIdx.x;
    int x = (i < n) ? in[i] : 0;
    sm[threadIdx.x] = x;
    __syncthreads();
    for (int off = 1; off < 1024; off <<= 1) {
        int y = (threadIdx.x >= (unsigned)off) ? sm[threadIdx.x - off] : 0;
        __syncthreads();
        sm[threadIdx.x] += y;
        __syncthreads();
    }
    if (i < n) local_excl[i] = sm[threadIdx.x] - x;
    if (threadIdx.x == 1023) partials[blockIdx.x] = sm[1023];
}

// stage 2: single block scans up to 1024 chunk totals; total stored at partials[1024]
__global__ void scan2_kernel(int* __restrict__ partials, int nchunks) {
    __shared__ int sm[1024];
    int x = (threadIdx.x < (unsigned)nchunks) ? partials[threadIdx.x] : 0;
    sm[threadIdx.x] = x;
    __syncthreads();
    for (int off = 1; off < 1024; off <<= 1) {
        int y = (threadIdx.x >= (unsigned)off) ? sm[threadIdx.x - off] : 0;
        __syncthreads();
        sm[threadIdx.x] += y;
        __syncthreads();
    }
    partials[threadIdx.x] = sm[threadIdx.x] - x;     // exclusive chunk offsets
    if (threadIdx.x == 1023) partials[1024] = sm[1023];
}

// stage 3: add chunk offsets; out[n] = grand total
__global__ void scan3_kernel(const int* __restrict__ local_excl, const int* __restrict__ partials,
                             int* __restrict__ out, int n) {
    int i = blockIdx.x * 1024 + threadIdx.x;
    if (i < n) out[i] = local_excl[i] + partials[blockIdx.x];
    if (i == n) out[n] = partials[1024];
}

// S3: multisplit — write packed (src<<7)|(dst&127) into per-(block,bucket) segments.
__global__ void bksplit_kernel(const int* __restrict__ src, const int* __restrict__ dst,
                               const int* __restrict__ bh_scan, unsigned* __restrict__ pairs,
                               int E, int NB, int chunk) {
    extern __shared__ int lm[];                      // lbase[NB] then lcnt[NB]
    int* lbase = lm;
    int* lcnt  = lm + NB;
    int b = blockIdx.x;
    for (int k = threadIdx.x; k < NB; k += blockDim.x) {
        lbase[k] = bh_scan[k * SBLOCKS + b];
        lcnt[k]  = 0;
    }
    __syncthreads();
    int beg = b * chunk, end = min(E, beg + chunk);
    for (int e = beg + (int)threadIdx.x; e < end; e += blockDim.x) {
        int d = dst[e];
        int k = d >> BKT_BITS;
        int pos = lbase[k] + atomicAdd(&lcnt[k], 1);
        pairs[pos] = ((unsigned)src[e] << BKT_BITS) | (unsigned)(d & BKT_MASK);
    }
}

// S4: one block per bucket — per-node degrees + LDS scan -> row_ptr, then local CSR scatter.
__global__ void csr_build_kernel(const unsigned* __restrict__ pairs, const int* __restrict__ bh_scan,
                                 int* __restrict__ row_ptr, int* __restrict__ csr_src,
                                 int E, int N, int NB) {
    __shared__ int ldeg[128];
    __shared__ int lscan[128];
    __shared__ int lpos[128];
    int k = blockIdx.x;
    int bbase = bh_scan[k * SBLOCKS];
    int bend  = bh_scan[(k + 1) * SBLOCKS];          // k==NB-1 reads bh_scan[NB*SBLOCKS]==E
    if (threadIdx.x < 128) ldeg[threadIdx.x] = 0;
    __syncthreads();
    for (int i = bbase + (int)threadIdx.x; i < bend; i += blockDim.x)
        atomicAdd(&ldeg[pairs[i] & BKT_MASK], 1);
    __syncthreads();
    int x = (threadIdx.x < 128) ? ldeg[threadIdx.x] : 0;
    if (threadIdx.x < 128) lscan[threadIdx.x] = x;
    __syncthreads();
    for (int off = 1; off < 128; off <<= 1) {
        int y = 0;
        if (threadIdx.x < 128 && threadIdx.x >= (unsigned)off) y = lscan[threadIdx.x - off];
        __syncthreads();
        if (threadIdx.x < 128) lscan[threadIdx.x] += y;
        __syncthreads();
    }
    if (threadIdx.x < 128) {
        int excl = lscan[threadIdx.x] - x;
        int node = (k << BKT_BITS) + threadIdx.x;
        if (node < N) row_ptr[node] = bbase + excl;
        lpos[threadIdx.x] = excl;
    }
    if (k == NB - 1 && threadIdx.x == 0) row_ptr[N] = E;
    __syncthreads();
    for (int i = bbase + (int)threadIdx.x; i < bend; i += blockDim.x) {
        unsigned p = pairs[i];
        int pos = atomicAdd(&lpos[p & BKT_MASK], 1);
        csr_src[bbase + pos] = (int)(p >> BKT_BITS);
    }
}

// ---------------- per-layer kernels ----------------

// one wave (64 lanes) per node: s[v] = h[v].w_src, t[v] = h[v].w_dst
__global__ void st_kernel(const float* __restrict__ h, const float* __restrict__ att_w_l,
                          float* __restrict__ s, float* __restrict__ t, int n) {
    int gid  = blockIdx.x * blockDim.x + threadIdx.x;
    int v    = gid >> 6;
    int lane = threadIdx.x & 63;
    if (v >= n) return;
    float2 hv = ((const float2*)(h + (size_t)v * 128))[lane];
    float2 ws = ((const float2*)att_w_l)[lane];
    float2 wd = ((const float2*)(att_w_l + 128))[lane];
    float ps = hv.x * ws.x + hv.y * ws.y;
    float pt = hv.x * wd.x + hv.y * wd.y;
    for (int off = 32; off > 0; off >>= 1) {
        ps += __shfl_down(ps, off);
        pt += __shfl_down(pt, off);
    }
    if (lane == 0) { s[v] = ps; t[v] = pt; }
}

// one wave per node: online softmax over in-edges, then weighted float4 gather.
// phase B: half-wave per edge (lane&31 owns 4 dims), unrolled to 8 edges = 4 gather chains.
__global__ void agg_kernel(const float* __restrict__ hin, const float* __restrict__ s,
                           const float* __restrict__ t, const int* __restrict__ row_ptr,
                           const int* __restrict__ csr_src, float* __restrict__ hout, int n) {
    int gid   = blockIdx.x * blockDim.x + threadIdx.x;
    int v     = gid >> 6;
    int lane  = threadIdx.x & 63;
    if (v >= n) return;
    int half  = lane >> 5;
    int hlane = lane & 31;

    int beg = row_ptr[v];
    int end = row_ptr[v + 1];
    float tv = t[v];

    // phase A: online softmax (m, l), lane-strided
    float m = NEG_BIG, l = 0.f;
    for (int i = beg + lane; i < end; i += 64) {
        int u = csr_src[i];
        float a = s[u] + tv;
        float e = (a > 0.f) ? a : NEG_SLOPE * a;
        float mn = fmaxf(m, e);
        l = l * __expf(m - mn) + __expf(e - mn);
        m = mn;
    }
    for (int off = 32; off > 0; off >>= 1) {
        float m2 = __shfl_down(m, off);
        float l2 = __shfl_down(l, off);
        float mn = fmaxf(m, m2);
        l = l * __expf(m - mn) + l2 * __expf(m2 - mn);
        m = mn;
    }
    m = __shfl(m, 0);
    l = __shfl(l, 0);
    float inv_l = (l > 0.f) ? (1.0f / l) : 0.f;      // deg-0 -> zero row, matches ref

    // phase B
    float4 acc = make_float4(0.f, 0.f, 0.f, 0.f);
    int i = beg;
    for (; i + 7 < end; i += 8) {                    // 8 edges, 4 independent gather chains
        int u0 = csr_src[i     + half];
        int u1 = csr_src[i + 2 + half];
        int u2 = csr_src[i + 4 + half];
        int u3 = csr_src[i + 6 + half];
        const float4 h0 = ((const float4*)(hin + (size_t)u0 * 128))[hlane];
        const float4 h1 = ((const float4*)(hin + (size_t)u1 * 128))[hlane];
        const float4 h2 = ((const float4*)(hin + (size_t)u2 * 128))[hlane];
        const float4 h3 = ((const float4*)(hin + (size_t)u3 * 128))[hlane];
        float a0 = s[u0] + tv, a1 = s[u1] + tv, a2 = s[u2] + tv, a3 = s[u3] + tv;
        float e0 = (a0 > 0.f) ? a0 : NEG_SLOPE * a0;
        float e1 = (a1 > 0.f) ? a1 : NEG_SLOPE * a1;
        float e2 = (a2 > 0.f) ? a2 : NEG_SLOPE * a2;
        float e3 = (a3 > 0.f) ? a3 : NEG_SLOPE * a3;
        float al0 = __expf(e0 - m) * inv_l;
        float al1 = __expf(e1 - m) * inv_l;
        float al2 = __expf(e2 - m) * inv_l;
        float al3 = __expf(e3 - m) * inv_l;
        acc.x = fmaf(al0, h0.x, acc.x); acc.y = fmaf(al0, h0.y, acc.y);
        acc.z = fmaf(al0, h0.z, acc.z); acc.w = fmaf(al0, h0.w, acc.w);
        acc.x = fmaf(al1, h1.x, acc.x); acc.y = fmaf(al1, h1.y, acc.y);
        acc.z = fmaf(al1, h1.z, acc.z); acc.w = fmaf(al1, h1.w, acc.w);
        acc.x = fmaf(al2, h2.x, acc.x); acc.y = fmaf(al2, h2.y, acc.y);
        acc.z = fmaf(al2, h2.z, acc.z); acc.w = fmaf(al2, h2.w, acc.w);
        acc.x = fmaf(al3, h3.x, acc.x); acc.y = fmaf(al3, h3.y, acc.y);
        acc.z = fmaf(al3, h3.z, acc.z); acc.w = fmaf(al3, h3.w, acc.w);
    }
    for (; i + 1 < end; i += 2) {
        int u = csr_src[i + half];
        float a = s[u] + tv;
        float e = (a > 0.f) ? a : NEG_SLOPE * a;
        float al = __expf(e - m) * inv_l;
        float4 hv = ((const float4*)(hin + (size_t)u * 128))[hlane];
        acc.x = fmaf(al, hv.x, acc.x); acc.y = fmaf(al, hv.y, acc.y);
        acc.z = fmaf(al, hv.z, acc.z); acc.w = fmaf(al, hv.w, acc.w);
    }
    if (i < end) {                                   // odd tail: half 1 contributes 0
        int u = csr_src[i];
        float a = s[u] + tv;
        float e = (a > 0.f) ? a : NEG_SLOPE * a;
        float al = (half == 0) ? __expf(e - m) * inv_l : 0.f;
        float4 hv = ((const float4*)(hin + (size_t)u * 128))[hlane];
        acc.x = fmaf(al, hv.x, acc.x); acc.y = fmaf(al, hv.y, acc.y);
        acc.z = fmaf(al, hv.z, acc.z); acc.w = fmaf(al, hv.w, acc.w);
    }
    acc.x += __shfl_xor(acc.x, 32);
    acc.y += __shfl_xor(acc.y, 32);
    acc.z += __shfl_xor(acc.z, 32);
    acc.w += __shfl_xor(acc.w, 32);
    if (half == 0)
        ((float4*)(hout + (size_t)v * 128))[hlane] = acc;
}

// ---------------- launch ----------------

extern "C" void kernel_launch(void* const* d_in, const int* in_sizes, int n_in,
                              void* d_out, int out_size, void* d_ws, size_t ws_size,
                              hipStream_t stream) {
    const float* h0    = (const float*)d_in[0];
    const int*   src   = (const int*)d_in[1];
    const int*   dst   = (const int*)d_in[2];
    const float* att_w = (const float*)d_in[3];
    int N = in_sizes[0] / 128;
    int E = in_sizes[1];
    int L = in_sizes[3] / 256;
    float* out = (float*)d_out;

    int NB = (N + BKT_MASK) >> BKT_BITS;     // 391 buckets
    int n2 = NB * SBLOCKS;                   // 50048 count-matrix entries
    int chunk = (E + SBLOCKS - 1) / SBLOCKS;
    int nch2 = (n2 + 1023) / 1024;           // 49 scan chunks (<=1024 required)

    char* ws = (char*)d_ws;
    size_t off = 0;
    auto alloc = [&](size_t bytes) -> void* {
        void* p = ws + off;
        off = (off + bytes + 511) & ~(size_t)511;
        return p;
    };
    int*      row_ptr   = (int*)     alloc((size_t)(N + 1) * 4);
    int*      csr_src   = (int*)     alloc((size_t)E * 4);
    float*    s         = (float*)   alloc((size_t)N * 4);
    float*    t         = (float*)   alloc((size_t)N * 4);
    float*    h1        = (float*)   alloc((size_t)N * 128 * 4);
    unsigned* pairs     = (unsigned*)alloc((size_t)E * 4);
    int*      blockhist = (int*)     alloc((size_t)n2 * 4);
    int*      bh_scan   = (int*)     alloc((size_t)(n2 + 1) * 4);
    int*      local_ex  = (int*)     alloc((size_t)n2 * 4);
    int*      partials  = (int*)     alloc(1025 * 4);

    bkhist_kernel<<<SBLOCKS, 256, NB * 4, stream>>>(dst, blockhist, E, NB, chunk);
    scan1_kernel<<<nch2, 1024, 0, stream>>>(blockhist, local_ex, partials, n2);
    scan2_kernel<<<1, 1024, 0, stream>>>(partials, nch2);
    scan3_kernel<<<nch2, 1024, 0, stream>>>(local_ex, partials, bh_scan, n2);
    bksplit_kernel<<<SBLOCKS, 256, 2 * NB * 4, stream>>>(src, dst, bh_scan, pairs, E, NB, chunk);
    csr_build_kernel<<<NB, 256, 0, stream>>>(pairs, bh_scan, row_ptr, csr_src, E, N, NB);

    const int tb = 256;
    int node_blocks = (N * 64 + tb - 1) / tb;        // one wave per node
    const float* hin = h0;
    for (int l = 0; l < L; ++l) {
        float* hout = (l == L - 1) ? out : h1;       // L==2: layer0 -> h1, layer1 -> out
        st_kernel<<<node_blocks, tb, 0, stream>>>(hin, att_w + (size_t)l * 256, s, t, N);
        agg_kernel<<<node_blocks, tb, 0, stream>>>(hin, s, t, row_ptr, csr_src, hout, N);
        hin = h1;
    }
}

// Round 5
// 345.935 us; speedup vs baseline: 1.9167x; 1.0655x over previous
//
#include <hip/hip_runtime.h>
#include <hip/hip_fp16.h>
#include <math.h>

#define NEG_SLOPE 0.01f
#define NEG_BIG  -1e30f   // finite sentinel: -INFINITY gives NaN in shuffle combine for deg<32
#define BKT_BITS 7        // 128 nodes per bucket
#define BKT_MASK 127
#define SBLOCKS  128      // blocks in the multisplit phases

// ---------------- bucketed CSR build ----------------

// S1: per-(block,bucket) histogram of dst>>7. blockhist[k*SBLOCKS + b].
__global__ void bkhist_kernel(const int* __restrict__ dst, int* __restrict__ blockhist,
                              int E, int NB, int chunk) {
    extern __shared__ int lh[];
    for (int k = threadIdx.x; k < NB; k += blockDim.x) lh[k] = 0;
    __syncthreads();
    int b = blockIdx.x;
    int beg = b * chunk, end = min(E, beg + chunk);
    for (int e = beg + (int)threadIdx.x; e < end; e += blockDim.x)
        atomicAdd(&lh[dst[e] >> BKT_BITS], 1);
    __syncthreads();
    for (int k = threadIdx.x; k < NB; k += blockDim.x)
        blockhist[k * SBLOCKS + b] = lh[k];
}

// S2: single-block fused exclusive scan of n (<= 1024*1024) ints; out[n] = total.
__global__ void scan_fused_kernel(const int* __restrict__ in, int* __restrict__ out, int n) {
    __shared__ int sm[1024];
    int C = (n + 1023) >> 10;
    int beg = (int)threadIdx.x * C, end = min(n, beg + C);
    int sum = 0;
    for (int i = beg; i < end; ++i) sum += in[i];
    sm[threadIdx.x] = sum;
    __syncthreads();
    for (int off = 1; off < 1024; off <<= 1) {
        int y = (threadIdx.x >= (unsigned)off) ? sm[threadIdx.x - off] : 0;
        __syncthreads();
        sm[threadIdx.x] += y;
        __syncthreads();
    }
    int run = sm[threadIdx.x] - sum;           // exclusive prefix of this thread's chunk
    for (int i = beg; i < end; ++i) { int x = in[i]; out[i] = run; run += x; }
    if (threadIdx.x == 1023) out[n] = sm[1023];
}

// S3: multisplit — packed (src<<7)|(dst&127) into per-(block,bucket) segments.
__global__ void bksplit_kernel(const int* __restrict__ src, const int* __restrict__ dst,
                               const int* __restrict__ bh_scan, unsigned* __restrict__ pairs,
                               int E, int NB, int chunk) {
    extern __shared__ int lm[];                // lbase[NB] then lcnt[NB]
    int* lbase = lm;
    int* lcnt  = lm + NB;
    int b = blockIdx.x;
    for (int k = threadIdx.x; k < NB; k += blockDim.x) {
        lbase[k] = bh_scan[k * SBLOCKS + b];
        lcnt[k]  = 0;
    }
    __syncthreads();
    int beg = b * chunk, end = min(E, beg + chunk);
    for (int e = beg + (int)threadIdx.x; e < end; e += blockDim.x) {
        int d = dst[e];
        int k = d >> BKT_BITS;
        int pos = lbase[k] + atomicAdd(&lcnt[k], 1);
        pairs[pos] = ((unsigned)src[e] << BKT_BITS) | (unsigned)(d & BKT_MASK);
    }
}

// S4: one block per bucket — per-node degrees + LDS scan -> row_ptr, then local CSR scatter.
__global__ void csr_build_kernel(const unsigned* __restrict__ pairs, const int* __restrict__ bh_scan,
                                 int* __restrict__ row_ptr, int* __restrict__ csr_src,
                                 int E, int N, int NB) {
    __shared__ int ldeg[128];
    __shared__ int lscan[128];
    __shared__ int lpos[128];
    int k = blockIdx.x;
    int bbase = bh_scan[k * SBLOCKS];
    int bend  = bh_scan[(k + 1) * SBLOCKS];    // k==NB-1 reads bh_scan[NB*SBLOCKS]==E
    if (threadIdx.x < 128) ldeg[threadIdx.x] = 0;
    __syncthreads();
    for (int i = bbase + (int)threadIdx.x; i < bend; i += blockDim.x)
        atomicAdd(&ldeg[pairs[i] & BKT_MASK], 1);
    __syncthreads();
    int x = (threadIdx.x < 128) ? ldeg[threadIdx.x] : 0;
    if (threadIdx.x < 128) lscan[threadIdx.x] = x;
    __syncthreads();
    for (int off = 1; off < 128; off <<= 1) {
        int y = 0;
        if (threadIdx.x < 128 && threadIdx.x >= (unsigned)off) y = lscan[threadIdx.x - off];
        __syncthreads();
        if (threadIdx.x < 128) lscan[threadIdx.x] += y;
        __syncthreads();
    }
    if (threadIdx.x < 128) {
        int excl = lscan[threadIdx.x] - x;
        int node = (k << BKT_BITS) + threadIdx.x;
        if (node < N) row_ptr[node] = bbase + excl;
        lpos[threadIdx.x] = excl;
    }
    if (k == NB - 1 && threadIdx.x == 0) row_ptr[N] = E;
    __syncthreads();
    for (int i = bbase + (int)threadIdx.x; i < bend; i += blockDim.x) {
        unsigned p = pairs[i];
        int pos = atomicAdd(&lpos[p & BKT_MASK], 1);
        csr_src[bbase + pos] = (int)(p >> BKT_BITS);
    }
}

// ---------------- per-layer kernels ----------------

// wave per node: s[v]=h.w_src, t[v]=h.w_dst, AND h -> fp16 copy (single read of h).
__global__ void stconv_kernel(const float* __restrict__ h, const float* __restrict__ att_w_l,
                              float* __restrict__ s, float* __restrict__ t,
                              __half* __restrict__ h16, int n) {
    int gid  = blockIdx.x * blockDim.x + threadIdx.x;
    int v    = gid >> 6;
    int lane = threadIdx.x & 63;
    if (v >= n) return;
    float2 hv = ((const float2*)(h + (size_t)v * 128))[lane];
    ((__half2*)(h16 + (size_t)v * 128))[lane] = __floats2half2_rn(hv.x, hv.y);
    float2 ws = ((const float2*)att_w_l)[lane];
    float2 wd = ((const float2*)(att_w_l + 128))[lane];
    float ps = hv.x * ws.x + hv.y * ws.y;
    float pt = hv.x * wd.x + hv.y * wd.y;
    for (int off = 32; off > 0; off >>= 1) {
        ps += __shfl_down(ps, off);
        pt += __shfl_down(pt, off);
    }
    if (lane == 0) { s[v] = ps; t[v] = pt; }
}

// one wave per node: online softmax, then weighted fp16 gather (fp32 accumulate).
// LAST=false: write h1 as fp16 + fused next-layer s2/t2. LAST=true: write fp32 out.
template<bool LAST>
__global__ void agg_kernel(const __half* __restrict__ hin, const float* __restrict__ s,
                           const float* __restrict__ t, const int* __restrict__ row_ptr,
                           const int* __restrict__ csr_src,
                           __half* __restrict__ hout16, float* __restrict__ outf,
                           const float* __restrict__ att_w_next,
                           float* __restrict__ s2, float* __restrict__ t2, int n) {
    int gid   = blockIdx.x * blockDim.x + threadIdx.x;
    int v     = gid >> 6;
    int lane  = threadIdx.x & 63;
    if (v >= n) return;
    int half  = lane >> 5;
    int hlane = lane & 31;

    int beg = row_ptr[v];
    int end = row_ptr[v + 1];
    float tv = t[v];

    // phase A: online softmax (m, l), lane-strided
    float m = NEG_BIG, l = 0.f;
    for (int i = beg + lane; i < end; i += 64) {
        int u = csr_src[i];
        float a = s[u] + tv;
        float e = (a > 0.f) ? a : NEG_SLOPE * a;
        float mn = fmaxf(m, e);
        l = l * __expf(m - mn) + __expf(e - mn);
        m = mn;
    }
    for (int off = 32; off > 0; off >>= 1) {
        float m2 = __shfl_down(m, off);
        float l2 = __shfl_down(l, off);
        float mn = fmaxf(m, m2);
        l = l * __expf(m - mn) + l2 * __expf(m2 - mn);
        m = mn;
    }
    m = __shfl(m, 0);
    l = __shfl(l, 0);
    float inv_l = (l > 0.f) ? (1.0f / l) : 0.f;      // deg-0 -> zero row, matches ref

    // phase B: half-wave per edge, lane&31 owns dims 4*hlane..+3 (8B fp16 loads),
    // unrolled 8 edges = 4 independent gather chains per half.
    float4 acc = make_float4(0.f, 0.f, 0.f, 0.f);
    int i = beg;
    #define GATHER(uu, al)                                                     \
        { float2 r = ((const float2*)(hin + (size_t)(uu) * 128))[hlane];       \
          float2 f01 = __half22float2(*(const __half2*)&r.x);                  \
          float2 f23 = __half22float2(*(const __half2*)&r.y);                  \
          acc.x = fmaf(al, f01.x, acc.x); acc.y = fmaf(al, f01.y, acc.y);      \
          acc.z = fmaf(al, f23.x, acc.z); acc.w = fmaf(al, f23.y, acc.w); }
    for (; i + 7 < end; i += 8) {
        int u0 = csr_src[i     + half];
        int u1 = csr_src[i + 2 + half];
        int u2 = csr_src[i + 4 + half];
        int u3 = csr_src[i + 6 + half];
        float a0 = s[u0] + tv, a1 = s[u1] + tv, a2 = s[u2] + tv, a3 = s[u3] + tv;
        float e0 = (a0 > 0.f) ? a0 : NEG_SLOPE * a0;
        float e1 = (a1 > 0.f) ? a1 : NEG_SLOPE * a1;
        float e2 = (a2 > 0.f) ? a2 : NEG_SLOPE * a2;
        float e3 = (a3 > 0.f) ? a3 : NEG_SLOPE * a3;
        float al0 = __expf(e0 - m) * inv_l;
        float al1 = __expf(e1 - m) * inv_l;
        float al2 = __expf(e2 - m) * inv_l;
        float al3 = __expf(e3 - m) * inv_l;
        GATHER(u0, al0); GATHER(u1, al1); GATHER(u2, al2); GATHER(u3, al3);
    }
    for (; i + 1 < end; i += 2) {
        int u = csr_src[i + half];
        float a = s[u] + tv;
        float e = (a > 0.f) ? a : NEG_SLOPE * a;
        float al = __expf(e - m) * inv_l;
        GATHER(u, al);
    }
    if (i < end) {                                   // odd tail: half 1 contributes 0
        int u = csr_src[i];
        float a = s[u] + tv;
        float e = (a > 0.f) ? a : NEG_SLOPE * a;
        float al = (half == 0) ? __expf(e - m) * inv_l : 0.f;
        GATHER(u, al);
    }
    #undef GATHER
    // combine the two half-wave partials; afterwards BOTH halves hold the full sum
    acc.x += __shfl_xor(acc.x, 32);
    acc.y += __shfl_xor(acc.y, 32);
    acc.z += __shfl_xor(acc.z, 32);
    acc.w += __shfl_xor(acc.w, 32);

    if (LAST) {
        if (half == 0)
            ((float4*)(outf + (size_t)v * 128))[hlane] = acc;
    } else {
        if (half == 0) {
            __half2 q01 = __floats2half2_rn(acc.x, acc.y);
            __half2 q23 = __floats2half2_rn(acc.z, acc.w);
            float2 packed;
            packed.x = *(const float*)&q01;
            packed.y = *(const float*)&q23;
            ((float2*)(hout16 + (size_t)v * 128))[hlane] = packed;
        }
        // fused next-layer s/t: dot acc (full row, 4 dims/lane over lanes 0..31) with w
        float4 ws4 = ((const float4*)att_w_next)[hlane];
        float4 wd4 = ((const float4*)(att_w_next + 128))[hlane];
        float ps = acc.x * ws4.x + acc.y * ws4.y + acc.z * ws4.z + acc.w * ws4.w;
        float pt = acc.x * wd4.x + acc.y * wd4.y + acc.z * wd4.z + acc.w * wd4.w;
        for (int off = 16; off > 0; off >>= 1) {     // lane0 sums lanes 0..31 only
            ps += __shfl_down(ps, off);
            pt += __shfl_down(pt, off);
        }
        if (lane == 0) { s2[v] = ps; t2[v] = pt; }
    }
}

// ---------------- launch ----------------

extern "C" void kernel_launch(void* const* d_in, const int* in_sizes, int n_in,
                              void* d_out, int out_size, void* d_ws, size_t ws_size,
                              hipStream_t stream) {
    const float* h0    = (const float*)d_in[0];
    const int*   src   = (const int*)d_in[1];
    const int*   dst   = (const int*)d_in[2];
    const float* att_w = (const float*)d_in[3];
    int N = in_sizes[0] / 128;
    int E = in_sizes[1];
    int L = in_sizes[3] / 256;
    float* out = (float*)d_out;

    int NB = (N + BKT_MASK) >> BKT_BITS;     // 391 buckets
    int n2 = NB * SBLOCKS;                   // 50048 count-matrix entries
    int chunk = (E + SBLOCKS - 1) / SBLOCKS;

    char* ws = (char*)d_ws;
    size_t off = 0;
    auto alloc = [&](size_t bytes) -> void* {
        void* p = ws + off;
        off = (off + bytes + 511) & ~(size_t)511;
        return p;
    };
    int*      row_ptr   = (int*)     alloc((size_t)(N + 1) * 4);
    int*      csr_src   = (int*)     alloc((size_t)E * 4);
    float*    s1        = (float*)   alloc((size_t)N * 4);
    float*    t1        = (float*)   alloc((size_t)N * 4);
    float*    s2        = (float*)   alloc((size_t)N * 4);
    float*    t2        = (float*)   alloc((size_t)N * 4);
    __half*   hA        = (__half*)  alloc((size_t)N * 128 * 2);
    __half*   hB        = (__half*)  alloc((size_t)N * 128 * 2);
    unsigned* pairs     = (unsigned*)alloc((size_t)E * 4);
    int*      blockhist = (int*)     alloc((size_t)n2 * 4);
    int*      bh_scan   = (int*)     alloc((size_t)(n2 + 1) * 4);

    bkhist_kernel<<<SBLOCKS, 256, NB * 4, stream>>>(dst, blockhist, E, NB, chunk);
    scan_fused_kernel<<<1, 1024, 0, stream>>>(blockhist, bh_scan, n2);
    bksplit_kernel<<<SBLOCKS, 256, 2 * NB * 4, stream>>>(src, dst, bh_scan, pairs, E, NB, chunk);
    csr_build_kernel<<<NB, 256, 0, stream>>>(pairs, bh_scan, row_ptr, csr_src, E, N, NB);

    const int tb = 256;
    int node_blocks = (N * 64 + tb - 1) / tb;        // one wave per node

    // layer 0 s/t + fp16 conversion (single pass over h0)
    stconv_kernel<<<node_blocks, tb, 0, stream>>>(h0, att_w, s1, t1, hA, N);

    __half* hin = hA;
    __half* hnx = hB;
    float *sc = s1, *tc = t1, *sn = s2, *tn = t2;
    for (int l = 0; l < L; ++l) {
        if (l == L - 1) {
            agg_kernel<true><<<node_blocks, tb, 0, stream>>>(
                hin, sc, tc, row_ptr, csr_src, nullptr, out, nullptr, nullptr, nullptr, N);
        } else {
            agg_kernel<false><<<node_blocks, tb, 0, stream>>>(
                hin, sc, tc, row_ptr, csr_src, hnx, nullptr,
                att_w + (size_t)(l + 1) * 256, sn, tn, N);
            __half* tmp = hin; hin = hnx; hnx = tmp;
            float* tf;
            tf = sc; sc = sn; sn = tf;
            tf = tc; tc = tn; tn = tf;
        }
    }
}

// Round 7
// 266.520 us; speedup vs baseline: 2.4878x; 1.2980x over previous
//
#include <hip/hip_runtime.h>
#include <hip/hip_fp16.h>
#include <math.h>

#define NEG_SLOPE 0.01f
#define BKT_BITS 7        // 128 nodes per bucket
#define BKT_MASK 127
#define SBLOCKS  128      // blocks in the multisplit phases

// ---------------- bucketed CSR build ----------------

// S1: per-(block,bucket) histogram of dst>>7. blockhist[k*SBLOCKS + b].
__global__ void bkhist_kernel(const int* __restrict__ dst, int* __restrict__ blockhist,
                              int E, int NB, int chunk) {
    extern __shared__ int lh[];
    for (int k = threadIdx.x; k < NB; k += blockDim.x) lh[k] = 0;
    __syncthreads();
    int b = blockIdx.x;
    int beg = b * chunk, end = min(E, beg + chunk);
    for (int e = beg + (int)threadIdx.x; e < end; e += blockDim.x)
        atomicAdd(&lh[dst[e] >> BKT_BITS], 1);
    __syncthreads();
    for (int k = threadIdx.x; k < NB; k += blockDim.x)
        blockhist[k * SBLOCKS + b] = lh[k];
}

// multi-block scan (round-4 proven version; single-block fused scan was a 77us
// regression: 1 CU, uncoalesced per-thread serial chunks, 0.15% occupancy)
__global__ void scan1_kernel(const int* __restrict__ in, int* __restrict__ local_excl,
                             int* __restrict__ partials, int n) {
    __shared__ int sm[1024];
    int i = blockIdx.x * 1024 + threadIdx.x;
    int x = (i < n) ? in[i] : 0;
    sm[threadIdx.x] = x;
    __syncthreads();
    for (int off = 1; off < 1024; off <<= 1) {
        int y = (threadIdx.x >= (unsigned)off) ? sm[threadIdx.x - off] : 0;
        __syncthreads();
        sm[threadIdx.x] += y;
        __syncthreads();
    }
    if (i < n) local_excl[i] = sm[threadIdx.x] - x;
    if (threadIdx.x == 1023) partials[blockIdx.x] = sm[1023];
}

__global__ void scan2_kernel(int* __restrict__ partials, int nchunks) {
    __shared__ int sm[1024];
    int x = (threadIdx.x < (unsigned)nchunks) ? partials[threadIdx.x] : 0;
    sm[threadIdx.x] = x;
    __syncthreads();
    for (int off = 1; off < 1024; off <<= 1) {
        int y = (threadIdx.x >= (unsigned)off) ? sm[threadIdx.x - off] : 0;
        __syncthreads();
        sm[threadIdx.x] += y;
        __syncthreads();
    }
    partials[threadIdx.x] = sm[threadIdx.x] - x;     // exclusive chunk offsets
    if (threadIdx.x == 1023) partials[1024] = sm[1023];
}

__global__ void scan3_kernel(const int* __restrict__ local_excl, const int* __restrict__ partials,
                             int* __restrict__ out, int n) {
    int i = blockIdx.x * 1024 + threadIdx.x;
    if (i < n) out[i] = local_excl[i] + partials[blockIdx.x];
    if (i == n) out[n] = partials[1024];
}

// S3: multisplit — packed (src<<7)|(dst&127) into per-(block,bucket) segments.
__global__ void bksplit_kernel(const int* __restrict__ src, const int* __restrict__ dst,
                               const int* __restrict__ bh_scan, unsigned* __restrict__ pairs,
                               int E, int NB, int chunk) {
    extern __shared__ int lm[];                // lbase[NB] then lcnt[NB]
    int* lbase = lm;
    int* lcnt  = lm + NB;
    int b = blockIdx.x;
    for (int k = threadIdx.x; k < NB; k += blockDim.x) {
        lbase[k] = bh_scan[k * SBLOCKS + b];
        lcnt[k]  = 0;
    }
    __syncthreads();
    int beg = b * chunk, end = min(E, beg + chunk);
    for (int e = beg + (int)threadIdx.x; e < end; e += blockDim.x) {
        int d = dst[e];
        int k = d >> BKT_BITS;
        int pos = lbase[k] + atomicAdd(&lcnt[k], 1);
        pairs[pos] = ((unsigned)src[e] << BKT_BITS) | (unsigned)(d & BKT_MASK);
    }
}

// S4: one block per bucket — per-node degrees + LDS scan -> row_ptr, then local CSR scatter.
__global__ void csr_build_kernel(const unsigned* __restrict__ pairs, const int* __restrict__ bh_scan,
                                 int* __restrict__ row_ptr, int* __restrict__ csr_src,
                                 int E, int N, int NB) {
    __shared__ int ldeg[128];
    __shared__ int lscan[128];
    __shared__ int lpos[128];
    int k = blockIdx.x;
    int bbase = bh_scan[k * SBLOCKS];
    int bend  = bh_scan[(k + 1) * SBLOCKS];    // k==NB-1 reads bh_scan[NB*SBLOCKS]==E
    if (threadIdx.x < 128) ldeg[threadIdx.x] = 0;
    __syncthreads();
    for (int i = bbase + (int)threadIdx.x; i < bend; i += blockDim.x)
        atomicAdd(&ldeg[pairs[i] & BKT_MASK], 1);
    __syncthreads();
    int x = (threadIdx.x < 128) ? ldeg[threadIdx.x] : 0;
    if (threadIdx.x < 128) lscan[threadIdx.x] = x;
    __syncthreads();
    for (int off = 1; off < 128; off <<= 1) {
        int y = 0;
        if (threadIdx.x < 128 && threadIdx.x >= (unsigned)off) y = lscan[threadIdx.x - off];
        __syncthreads();
        if (threadIdx.x < 128) lscan[threadIdx.x] += y;
        __syncthreads();
    }
    if (threadIdx.x < 128) {
        int excl = lscan[threadIdx.x] - x;
        int node = (k << BKT_BITS) + threadIdx.x;
        if (node < N) row_ptr[node] = bbase + excl;
        lpos[threadIdx.x] = excl;
    }
    if (k == NB - 1 && threadIdx.x == 0) row_ptr[N] = E;
    __syncthreads();
    for (int i = bbase + (int)threadIdx.x; i < bend; i += blockDim.x) {
        unsigned p = pairs[i];
        int pos = atomicAdd(&lpos[p & BKT_MASK], 1);
        csr_src[bbase + pos] = (int)(p >> BKT_BITS);
    }
}

// ---------------- per-layer kernels ----------------

// wave per node: s[v]=h.w_src, t[v]=h.w_dst, AND h -> fp16 copy (single read of h).
__global__ void stconv_kernel(const float* __restrict__ h, const float* __restrict__ att_w_l,
                              float* __restrict__ s, float* __restrict__ t,
                              __half* __restrict__ h16, int n) {
    int gid  = blockIdx.x * blockDim.x + threadIdx.x;
    int v    = gid >> 6;
    int lane = threadIdx.x & 63;
    if (v >= n) return;
    float2 hv = ((const float2*)(h + (size_t)v * 128))[lane];
    ((__half2*)(h16 + (size_t)v * 128))[lane] = __floats2half2_rn(hv.x, hv.y);
    float2 ws = ((const float2*)att_w_l)[lane];
    float2 wd = ((const float2*)(att_w_l + 128))[lane];
    float ps = hv.x * ws.x + hv.y * ws.y;
    float pt = hv.x * wd.x + hv.y * wd.y;
    for (int off = 32; off > 0; off >>= 1) {
        ps += __shfl_down(ps, off);
        pt += __shfl_down(pt, off);
    }
    if (lane == 0) { s[v] = ps; t[v] = pt; }
}

// one wave per node, SINGLE PASS: unnormalized acc += exp(e)*h_u and l += exp(e),
// then scale by 1/l. Valid because alpha = exp(e)/sum(exp(e)) and logits here are
// bounded (|a| ~< 10; exp never overflows fp32) — no max-subtraction needed.
// Half-wave per edge (lane&31 owns 4 dims), 8-edge unroll = 4 gather chains/half.
// NOTE: macro param must NOT be named 'w' — it would substitute into 'acc.w'.
template<bool LAST>
__global__ void agg_kernel(const __half* __restrict__ hin, const float* __restrict__ s,
                           const float* __restrict__ t, const int* __restrict__ row_ptr,
                           const int* __restrict__ csr_src,
                           __half* __restrict__ hout16, float* __restrict__ outf,
                           const float* __restrict__ att_w_next,
                           float* __restrict__ s2, float* __restrict__ t2, int n) {
    int gid   = blockIdx.x * blockDim.x + threadIdx.x;
    int v     = gid >> 6;
    int lane  = threadIdx.x & 63;
    if (v >= n) return;
    int half  = lane >> 5;
    int hlane = lane & 31;

    int beg = row_ptr[v];
    int end = row_ptr[v + 1];
    float tv = t[v];

    float4 acc = make_float4(0.f, 0.f, 0.f, 0.f);
    float lsum = 0.f;                          // duplicated across the 32 lanes of a half
    int i = beg;
    #define GATHER(uu, wgt)                                                    \
        { float2 r = ((const float2*)(hin + (size_t)(uu) * 128))[hlane];       \
          float2 f01 = __half22float2(*(const __half2*)&r.x);                  \
          float2 f23 = __half22float2(*(const __half2*)&r.y);                  \
          acc.x = fmaf(wgt, f01.x, acc.x); acc.y = fmaf(wgt, f01.y, acc.y);    \
          acc.z = fmaf(wgt, f23.x, acc.z); acc.w = fmaf(wgt, f23.y, acc.w); }
    for (; i + 7 < end; i += 8) {
        int u0 = csr_src[i     + half];
        int u1 = csr_src[i + 2 + half];
        int u2 = csr_src[i + 4 + half];
        int u3 = csr_src[i + 6 + half];
        float a0 = s[u0] + tv, a1 = s[u1] + tv, a2 = s[u2] + tv, a3 = s[u3] + tv;
        float e0 = (a0 > 0.f) ? a0 : NEG_SLOPE * a0;
        float e1 = (a1 > 0.f) ? a1 : NEG_SLOPE * a1;
        float e2 = (a2 > 0.f) ? a2 : NEG_SLOPE * a2;
        float e3 = (a3 > 0.f) ? a3 : NEG_SLOPE * a3;
        float w0 = __expf(e0), w1 = __expf(e1), w2 = __expf(e2), w3 = __expf(e3);
        lsum += (w0 + w1) + (w2 + w3);
        GATHER(u0, w0); GATHER(u1, w1); GATHER(u2, w2); GATHER(u3, w3);
    }
    for (; i + 1 < end; i += 2) {
        int u = csr_src[i + half];
        float a = s[u] + tv;
        float e = (a > 0.f) ? a : NEG_SLOPE * a;
        float wu = __expf(e);
        lsum += wu;
        GATHER(u, wu);
    }
    if (i < end) {                             // odd tail: half 1 contributes 0
        int u = csr_src[i];
        float a = s[u] + tv;
        float e = (a > 0.f) ? a : NEG_SLOPE * a;
        float wu = (half == 0) ? __expf(e) : 0.f;
        lsum += wu;
        GATHER(u, wu);
    }
    #undef GATHER
    // combine the two half-wave partials; afterwards BOTH halves hold full sums
    acc.x += __shfl_xor(acc.x, 32);
    acc.y += __shfl_xor(acc.y, 32);
    acc.z += __shfl_xor(acc.z, 32);
    acc.w += __shfl_xor(acc.w, 32);
    lsum  += __shfl_xor(lsum, 32);
    float inv_l = (lsum > 0.f) ? (1.0f / lsum) : 0.f;   // deg-0 -> zero row
    acc.x *= inv_l; acc.y *= inv_l; acc.z *= inv_l; acc.w *= inv_l;

    if (LAST) {
        if (half == 0)
            ((float4*)(outf + (size_t)v * 128))[hlane] = acc;
    } else {
        if (half == 0) {
            __half2 q01 = __floats2half2_rn(acc.x, acc.y);
            __half2 q23 = __floats2half2_rn(acc.z, acc.w);
            float2 packed;
            packed.x = *(const float*)&q01;
            packed.y = *(const float*)&q23;
            ((float2*)(hout16 + (size_t)v * 128))[hlane] = packed;
        }
        // fused next-layer s/t: dot full row (4 dims/lane over lanes 0..31) with w
        float4 ws4 = ((const float4*)att_w_next)[hlane];
        float4 wd4 = ((const float4*)(att_w_next + 128))[hlane];
        float ps = acc.x * ws4.x + acc.y * ws4.y + acc.z * ws4.z + acc.w * ws4.w;
        float pt = acc.x * wd4.x + acc.y * wd4.y + acc.z * wd4.z + acc.w * wd4.w;
        for (int off = 16; off > 0; off >>= 1) {        // lane0 sums lanes 0..31
            ps += __shfl_down(ps, off);
            pt += __shfl_down(pt, off);
        }
        if (lane == 0) { s2[v] = ps; t2[v] = pt; }
    }
}

// ---------------- launch ----------------

extern "C" void kernel_launch(void* const* d_in, const int* in_sizes, int n_in,
                              void* d_out, int out_size, void* d_ws, size_t ws_size,
                              hipStream_t stream) {
    const float* h0    = (const float*)d_in[0];
    const int*   src   = (const int*)d_in[1];
    const int*   dst   = (const int*)d_in[2];
    const float* att_w = (const float*)d_in[3];
    int N = in_sizes[0] / 128;
    int E = in_sizes[1];
    int L = in_sizes[3] / 256;
    float* out = (float*)d_out;

    int NB = (N + BKT_MASK) >> BKT_BITS;     // 391 buckets
    int n2 = NB * SBLOCKS;                   // 50048 count-matrix entries
    int chunk = (E + SBLOCKS - 1) / SBLOCKS;
    int nch2 = (n2 + 1023) / 1024;           // 49 scan chunks (<=1024 required)

    char* ws = (char*)d_ws;
    size_t off = 0;
    auto alloc = [&](size_t bytes) -> void* {
        void* p = ws + off;
        off = (off + bytes + 511) & ~(size_t)511;
        return p;
    };
    int*      row_ptr   = (int*)     alloc((size_t)(N + 1) * 4);
    int*      csr_src   = (int*)     alloc((size_t)E * 4);
    float*    s1        = (float*)   alloc((size_t)N * 4);
    float*    t1        = (float*)   alloc((size_t)N * 4);
    float*    s2        = (float*)   alloc((size_t)N * 4);
    float*    t2        = (float*)   alloc((size_t)N * 4);
    __half*   hA        = (__half*)  alloc((size_t)N * 128 * 2);
    __half*   hB        = (__half*)  alloc((size_t)N * 128 * 2);
    unsigned* pairs     = (unsigned*)alloc((size_t)E * 4);
    int*      blockhist = (int*)     alloc((size_t)n2 * 4);
    int*      bh_scan   = (int*)     alloc((size_t)(n2 + 1) * 4);
    int*      local_ex  = (int*)     alloc((size_t)n2 * 4);
    int*      partials  = (int*)     alloc(1025 * 4);

    bkhist_kernel<<<SBLOCKS, 256, NB * 4, stream>>>(dst, blockhist, E, NB, chunk);
    scan1_kernel<<<nch2, 1024, 0, stream>>>(blockhist, local_ex, partials, n2);
    scan2_kernel<<<1, 1024, 0, stream>>>(partials, nch2);
    scan3_kernel<<<nch2, 1024, 0, stream>>>(local_ex, partials, bh_scan, n2);
    bksplit_kernel<<<SBLOCKS, 256, 2 * NB * 4, stream>>>(src, dst, bh_scan, pairs, E, NB, chunk);
    csr_build_kernel<<<NB, 256, 0, stream>>>(pairs, bh_scan, row_ptr, csr_src, E, N, NB);

    const int tb = 256;
    int node_blocks = (N * 64 + tb - 1) / tb;        // one wave per node

    // layer 0 s/t + fp16 conversion (single pass over h0)
    stconv_kernel<<<node_blocks, tb, 0, stream>>>(h0, att_w, s1, t1, hA, N);

    __half* hin = hA;
    __half* hnx = hB;
    float *sc = s1, *tc = t1, *sn = s2, *tn = t2;
    for (int l = 0; l < L; ++l) {
        if (l == L - 1) {
            agg_kernel<true><<<node_blocks, tb, 0, stream>>>(
                hin, sc, tc, row_ptr, csr_src, nullptr, out, nullptr, nullptr, nullptr, N);
        } else {
            agg_kernel<false><<<node_blocks, tb, 0, stream>>>(
                hin, sc, tc, row_ptr, csr_src, hnx, nullptr,
                att_w + (size_t)(l + 1) * 256, sn, tn, N);
            __half* tmp = hin; hin = hnx; hnx = tmp;
            float* tf;
            tf = sc; sc = sn; sn = tf;
            tf = tc; tc = tn; tn = tf;
        }
    }
}

// Round 8
// 238.164 us; speedup vs baseline: 2.7840x; 1.1191x over previous
//
#include <hip/hip_runtime.h>
#include <hip/hip_fp16.h>
#include <math.h>

#define NEG_SLOPE 0.01f
#define BKT_BITS 7        // 128 nodes per bucket
#define BKT_MASK 127
#define SBLOCKS  256      // blocks in the multisplit phases (512 thr each -> 8 waves/CU)
#define STPB     512      // threads per multisplit block

// ---------------- bucketed CSR build ----------------

// S1: per-(block,bucket) histogram of dst>>7. blockhist[k*SBLOCKS + b].
__global__ void bkhist_kernel(const int* __restrict__ dst, int* __restrict__ blockhist,
                              int E, int NB, int chunk) {
    extern __shared__ int lh[];
    for (int k = threadIdx.x; k < NB; k += blockDim.x) lh[k] = 0;
    __syncthreads();
    int b = blockIdx.x;
    int beg = b * chunk, end = min(E, beg + chunk);
    for (int e = beg + (int)threadIdx.x; e < end; e += blockDim.x)
        atomicAdd(&lh[dst[e] >> BKT_BITS], 1);
    __syncthreads();
    for (int k = threadIdx.x; k < NB; k += blockDim.x)
        blockhist[k * SBLOCKS + b] = lh[k];
}

// multi-block scan (round-4 proven; single-block fused scan was a 77us regression)
__global__ void scan1_kernel(const int* __restrict__ in, int* __restrict__ local_excl,
                             int* __restrict__ partials, int n) {
    __shared__ int sm[1024];
    int i = blockIdx.x * 1024 + threadIdx.x;
    int x = (i < n) ? in[i] : 0;
    sm[threadIdx.x] = x;
    __syncthreads();
    for (int off = 1; off < 1024; off <<= 1) {
        int y = (threadIdx.x >= (unsigned)off) ? sm[threadIdx.x - off] : 0;
        __syncthreads();
        sm[threadIdx.x] += y;
        __syncthreads();
    }
    if (i < n) local_excl[i] = sm[threadIdx.x] - x;
    if (threadIdx.x == 1023) partials[blockIdx.x] = sm[1023];
}

__global__ void scan2_kernel(int* __restrict__ partials, int nchunks) {
    __shared__ int sm[1024];
    int x = (threadIdx.x < (unsigned)nchunks) ? partials[threadIdx.x] : 0;
    sm[threadIdx.x] = x;
    __syncthreads();
    for (int off = 1; off < 1024; off <<= 1) {
        int y = (threadIdx.x >= (unsigned)off) ? sm[threadIdx.x - off] : 0;
        __syncthreads();
        sm[threadIdx.x] += y;
        __syncthreads();
    }
    partials[threadIdx.x] = sm[threadIdx.x] - x;     // exclusive chunk offsets
    if (threadIdx.x == 1023) partials[1024] = sm[1023];
}

__global__ void scan3_kernel(const int* __restrict__ local_excl, const int* __restrict__ partials,
                             int* __restrict__ out, int n) {
    int i = blockIdx.x * 1024 + threadIdx.x;
    if (i < n) out[i] = local_excl[i] + partials[blockIdx.x];
    if (i == n) out[n] = partials[1024];
}

// S3: multisplit — packed (src<<7)|(dst&127) into per-(block,bucket) segments.
__global__ void bksplit_kernel(const int* __restrict__ src, const int* __restrict__ dst,
                               const int* __restrict__ bh_scan, unsigned* __restrict__ pairs,
                               int E, int NB, int chunk) {
    extern __shared__ int lm[];                // lbase[NB] then lcnt[NB]
    int* lbase = lm;
    int* lcnt  = lm + NB;
    int b = blockIdx.x;
    for (int k = threadIdx.x; k < NB; k += blockDim.x) {
        lbase[k] = bh_scan[k * SBLOCKS + b];
        lcnt[k]  = 0;
    }
    __syncthreads();
    int beg = b * chunk, end = min(E, beg + chunk);
    for (int e = beg + (int)threadIdx.x; e < end; e += blockDim.x) {
        int d = dst[e];
        int k = d >> BKT_BITS;
        int pos = lbase[k] + atomicAdd(&lcnt[k], 1);
        pairs[pos] = ((unsigned)src[e] << BKT_BITS) | (unsigned)(d & BKT_MASK);
    }
}

// S4: one block per bucket — per-node degrees + LDS scan -> row_ptr, then local CSR scatter.
__global__ void csr_build_kernel(const unsigned* __restrict__ pairs, const int* __restrict__ bh_scan,
                                 int* __restrict__ row_ptr, int* __restrict__ csr_src,
                                 int E, int N, int NB) {
    __shared__ int ldeg[128];
    __shared__ int lscan[128];
    __shared__ int lpos[128];
    int k = blockIdx.x;
    int bbase = bh_scan[k * SBLOCKS];
    int bend  = bh_scan[(k + 1) * SBLOCKS];    // k==NB-1 reads bh_scan[NB*SBLOCKS]==E
    if (threadIdx.x < 128) ldeg[threadIdx.x] = 0;
    __syncthreads();
    for (int i = bbase + (int)threadIdx.x; i < bend; i += blockDim.x)
        atomicAdd(&ldeg[pairs[i] & BKT_MASK], 1);
    __syncthreads();
    int x = (threadIdx.x < 128) ? ldeg[threadIdx.x] : 0;
    if (threadIdx.x < 128) lscan[threadIdx.x] = x;
    __syncthreads();
    for (int off = 1; off < 128; off <<= 1) {
        int y = 0;
        if (threadIdx.x < 128 && threadIdx.x >= (unsigned)off) y = lscan[threadIdx.x - off];
        __syncthreads();
        if (threadIdx.x < 128) lscan[threadIdx.x] += y;
        __syncthreads();
    }
    if (threadIdx.x < 128) {
        int excl = lscan[threadIdx.x] - x;
        int node = (k << BKT_BITS) + threadIdx.x;
        if (node < N) row_ptr[node] = bbase + excl;
        lpos[threadIdx.x] = excl;
    }
    if (k == NB - 1 && threadIdx.x == 0) row_ptr[N] = E;
    __syncthreads();
    for (int i = bbase + (int)threadIdx.x; i < bend; i += blockDim.x) {
        unsigned p = pairs[i];
        int pos = atomicAdd(&lpos[p & BKT_MASK], 1);
        csr_src[bbase + pos] = (int)(p >> BKT_BITS);
    }
}

// ---------------- per-layer kernels ----------------

// wave per node: s[v]=h.w_src, t[v]=h.w_dst, AND h -> fp16 copy (single read of h).
__global__ void stconv_kernel(const float* __restrict__ h, const float* __restrict__ att_w_l,
                              float* __restrict__ s, float* __restrict__ t,
                              __half* __restrict__ h16, int n) {
    int gid  = blockIdx.x * blockDim.x + threadIdx.x;
    int v    = gid >> 6;
    int lane = threadIdx.x & 63;
    if (v >= n) return;
    float2 hv = ((const float2*)(h + (size_t)v * 128))[lane];
    ((__half2*)(h16 + (size_t)v * 128))[lane] = __floats2half2_rn(hv.x, hv.y);
    float2 ws = ((const float2*)att_w_l)[lane];
    float2 wd = ((const float2*)(att_w_l + 128))[lane];
    float ps = hv.x * ws.x + hv.y * ws.y;
    float pt = hv.x * wd.x + hv.y * wd.y;
    for (int off = 32; off > 0; off >>= 1) {
        ps += __shfl_down(ps, off);
        pt += __shfl_down(pt, off);
    }
    if (lane == 0) { s[v] = ps; t[v] = pt; }
}

__device__ __forceinline__ void gath(const __half* __restrict__ hin, int uu, float wgt,
                                     int hlane, float4& acc) {
    float2 r = ((const float2*)(hin + (size_t)uu * 128))[hlane];   // 4 fp16 dims
    float2 f01 = __half22float2(*(const __half2*)&r.x);
    float2 f23 = __half22float2(*(const __half2*)&r.y);
    acc.x = fmaf(wgt, f01.x, acc.x); acc.y = fmaf(wgt, f01.y, acc.y);
    acc.z = fmaf(wgt, f23.x, acc.z); acc.w = fmaf(wgt, f23.y, acc.w);
}

// one wave per node, single pass, EDGE-TILED:
//  - tile of up to 64 edges: lane j loads csr_src (coalesced) + s[u] (1 gather) and
//    computes ONE exp per edge (was 32x redundant per edge in round 7 -> VALUBusy 61%).
//    Lanes >= cnt clamp the index and get w=0, which also absorbs odd tails.
//  - gather loop: 2 edges/step (half-wave owns 4 dims via hlane); (u,w) broadcast from
//    the owning lane via variable-lane __shfl (ds_bpermute). Unroll 2 = 4 edges in flight.
// Unnormalized sum (logits bounded, |a|<~10 -> no overflow), scale by 1/lsum at end.
template<bool LAST>
__global__ void agg_kernel(const __half* __restrict__ hin, const float* __restrict__ s,
                           const float* __restrict__ t, const int* __restrict__ row_ptr,
                           const int* __restrict__ csr_src,
                           __half* __restrict__ hout16, float* __restrict__ outf,
                           const float* __restrict__ att_w_next,
                           float* __restrict__ s2, float* __restrict__ t2, int n) {
    int gid   = blockIdx.x * blockDim.x + threadIdx.x;
    int v     = gid >> 6;
    int lane  = threadIdx.x & 63;
    if (v >= n) return;
    int half  = lane >> 5;
    int hlane = lane & 31;

    int beg = row_ptr[v];
    int end = row_ptr[v + 1];
    float tv = t[v];

    float4 acc = make_float4(0.f, 0.f, 0.f, 0.f);
    float lsum_l = 0.f;                        // per-lane partial of sum(exp)

    for (int base = beg; base < end; base += 64) {
        int cnt = end - base;                  // >= 1
        if (cnt > 64) cnt = 64;
        // step 1: per-lane edge metadata (one exp per EDGE)
        int idx = base + min(lane, cnt - 1);   // clamp keeps address valid; w=0 below
        int u   = csr_src[idx];
        float a = s[u] + tv;
        float e = (a > 0.f) ? a : NEG_SLOPE * a;
        float wl = (lane < cnt) ? __expf(e) : 0.f;
        lsum_l += wl;
        // step 2: gather, 2 edges per step; broadcast (u,w) from owning lane
        int steps = (cnt + 1) >> 1;
        int k = 0;
        for (; k + 1 < steps; k += 2) {
            int sl0 = (k << 1) + half;         // this half's edge of pair k
            int sl1 = (k << 1) + 2 + half;     // ... of pair k+1
            int   u0 = __shfl(u, sl0);
            float w0 = __shfl(wl, sl0);
            int   u1 = __shfl(u, sl1);
            float w1 = __shfl(wl, sl1);
            gath(hin, u0, w0, hlane, acc);
            gath(hin, u1, w1, hlane, acc);
        }
        if (k < steps) {
            int sl = (k << 1) + half;          // if sl >= cnt: w=0, u clamped-valid
            int   u0 = __shfl(u, sl);
            float w0 = __shfl(wl, sl);
            gath(hin, u0, w0, hlane, acc);
        }
    }
    // reduce lsum across the wave (butterfly), combine half-wave acc partials
    float lsum = lsum_l;
    for (int off = 32; off > 0; off >>= 1) lsum += __shfl_xor(lsum, off);
    acc.x += __shfl_xor(acc.x, 32);
    acc.y += __shfl_xor(acc.y, 32);
    acc.z += __shfl_xor(acc.z, 32);
    acc.w += __shfl_xor(acc.w, 32);
    float inv_l = (lsum > 0.f) ? (1.0f / lsum) : 0.f;   // deg-0 -> zero row
    acc.x *= inv_l; acc.y *= inv_l; acc.z *= inv_l; acc.w *= inv_l;

    if (LAST) {
        if (half == 0)
            ((float4*)(outf + (size_t)v * 128))[hlane] = acc;
    } else {
        if (half == 0) {
            __half2 q01 = __floats2half2_rn(acc.x, acc.y);
            __half2 q23 = __floats2half2_rn(acc.z, acc.w);
            float2 packed;
            packed.x = *(const float*)&q01;
            packed.y = *(const float*)&q23;
            ((float2*)(hout16 + (size_t)v * 128))[hlane] = packed;
        }
        // fused next-layer s/t: dot full row (4 dims/lane over lanes 0..31) with w
        float4 ws4 = ((const float4*)att_w_next)[hlane];
        float4 wd4 = ((const float4*)(att_w_next + 128))[hlane];
        float ps = acc.x * ws4.x + acc.y * ws4.y + acc.z * ws4.z + acc.w * ws4.w;
        float pt = acc.x * wd4.x + acc.y * wd4.y + acc.z * wd4.z + acc.w * wd4.w;
        for (int off = 16; off > 0; off >>= 1) {        // lane0 sums lanes 0..31
            ps += __shfl_down(ps, off);
            pt += __shfl_down(pt, off);
        }
        if (lane == 0) { s2[v] = ps; t2[v] = pt; }
    }
}

// ---------------- launch ----------------

extern "C" void kernel_launch(void* const* d_in, const int* in_sizes, int n_in,
                              void* d_out, int out_size, void* d_ws, size_t ws_size,
                              hipStream_t stream) {
    const float* h0    = (const float*)d_in[0];
    const int*   src   = (const int*)d_in[1];
    const int*   dst   = (const int*)d_in[2];
    const float* att_w = (const float*)d_in[3];
    int N = in_sizes[0] / 128;
    int E = in_sizes[1];
    int L = in_sizes[3] / 256;
    float* out = (float*)d_out;

    int NB = (N + BKT_MASK) >> BKT_BITS;     // 391 buckets
    int n2 = NB * SBLOCKS;                   // 100096 count-matrix entries
    int chunk = (E + SBLOCKS - 1) / SBLOCKS;
    int nch2 = (n2 + 1023) / 1024;           // 98 scan chunks (<=1024 required)

    char* ws = (char*)d_ws;
    size_t off = 0;
    auto alloc = [&](size_t bytes) -> void* {
        void* p = ws + off;
        off = (off + bytes + 511) & ~(size_t)511;
        return p;
    };
    int*      row_ptr   = (int*)     alloc((size_t)(N + 1) * 4);
    int*      csr_src   = (int*)     alloc((size_t)E * 4);
    float*    s1        = (float*)   alloc((size_t)N * 4);
    float*    t1        = (float*)   alloc((size_t)N * 4);
    float*    s2        = (float*)   alloc((size_t)N * 4);
    float*    t2        = (float*)   alloc((size_t)N * 4);
    __half*   hA        = (__half*)  alloc((size_t)N * 128 * 2);
    __half*   hB        = (__half*)  alloc((size_t)N * 128 * 2);
    unsigned* pairs     = (unsigned*)alloc((size_t)E * 4);
    int*      blockhist = (int*)     alloc((size_t)n2 * 4);
    int*      bh_scan   = (int*)     alloc((size_t)(n2 + 1) * 4);
    int*      local_ex  = (int*)     alloc((size_t)n2 * 4);
    int*      partials  = (int*)     alloc(1025 * 4);

    bkhist_kernel<<<SBLOCKS, STPB, NB * 4, stream>>>(dst, blockhist, E, NB, chunk);
    scan1_kernel<<<nch2, 1024, 0, stream>>>(blockhist, local_ex, partials, n2);
    scan2_kernel<<<1, 1024, 0, stream>>>(partials, nch2);
    scan3_kernel<<<nch2, 1024, 0, stream>>>(local_ex, partials, bh_scan, n2);
    bksplit_kernel<<<SBLOCKS, STPB, 2 * NB * 4, stream>>>(src, dst, bh_scan, pairs, E, NB, chunk);
    csr_build_kernel<<<NB, 512, 0, stream>>>(pairs, bh_scan, row_ptr, csr_src, E, N, NB);

    const int tb = 256;
    int node_blocks = (N * 64 + tb - 1) / tb;        // one wave per node

    // layer 0 s/t + fp16 conversion (single pass over h0)
    stconv_kernel<<<node_blocks, tb, 0, stream>>>(h0, att_w, s1, t1, hA, N);

    __half* hin = hA;
    __half* hnx = hB;
    float *sc = s1, *tc = t1, *sn = s2, *tn = t2;
    for (int l = 0; l < L; ++l) {
        if (l == L - 1) {
            agg_kernel<true><<<node_blocks, tb, 0, stream>>>(
                hin, sc, tc, row_ptr, csr_src, nullptr, out, nullptr, nullptr, nullptr, N);
        } else {
            agg_kernel<false><<<node_blocks, tb, 0, stream>>>(
                hin, sc, tc, row_ptr, csr_src, hnx, nullptr,
                att_w + (size_t)(l + 1) * 256, sn, tn, N);
            __half* tmp = hin; hin = hnx; hnx = tmp;
            float* tf;
            tf = sc; sc = sn; sn = tf;
            tf = tc; tc = tn; tn = tf;
        }
    }
}